// Round 13
// baseline (343.820 us; speedup 1.0000x reference)
//
#include <hip/hip_runtime.h>
#include <hip/hip_bf16.h>
#include <math.h>

#define N_TOTAL 32768
#define E_TOTAL 524288
#define NUM_GRAPHS 64
#define NPG 512
#define KTOP 64
#define LATENT 513
#define PPAD 524

typedef __attribute__((ext_vector_type(8))) short bf16x8;
typedef __attribute__((ext_vector_type(4))) float f32x4;

__device__ __forceinline__ unsigned short f2bf(float f) {
    unsigned u = __float_as_uint(f);
    return (unsigned short)((u + 0x7FFFu + ((u >> 16) & 1u)) >> 16);   // RNE
}
__device__ __forceinline__ float bf2f(unsigned short h) {
    return __uint_as_float(((unsigned)h) << 16);
}
// XOR-swizzle within 128B granule keyed by row (LDS write AND read sides)
__device__ __forceinline__ int swz(int bir, int row) {
    return (bir & ~127) | ((bir & 127) ^ ((row & 7) << 4));
}
// 8 x u8 (exact small ints) -> bf16x8; ints <=255 are exact in bf16 (top-16 of f32)
__device__ __forceinline__ bf16x8 u8tobf(uint2 w8) {
    union { unsigned u[4]; bf16x8 v; } x;
#pragma unroll
    for (int j = 0; j < 4; ++j) {
        unsigned word = (j < 2) ? w8.x : w8.y;
        int sh = (j & 1) * 16;
        float a = (float)((word >> sh) & 0xFFu);
        float b = (float)((word >> (sh + 8)) & 0xFFu);
        x.u[j] = (__float_as_uint(a) >> 16) | (__float_as_uint(b) & 0xFFFF0000u);
    }
    return x.v;
}

// ---------------- setup ----------------

__global__ __launch_bounds__(256) void k_init(int* __restrict__ deg, int* __restrict__ cnt) {
    int i = blockIdx.x * 256 + threadIdx.x;
    if (i < N_TOTAL) { deg[i] = 1; cnt[i] = 0; }
}

__global__ __launch_bounds__(256) void k_build(const int* __restrict__ ei,
                                               int* __restrict__ deg, int* __restrict__ cnt) {
    int e = blockIdx.x * 256 + threadIdx.x;
    if (e >= E_TOTAL) return;
    atomicAdd(&deg[ei[e]], 1);
    atomicAdd(&cnt[ei[E_TOTAL + e]], 1);
}

// Dense u8 A'[g][v][u] (count + I) built per (graph, 64-row slice) in LDS.
__global__ __launch_bounds__(256) void k_buildA(const int* __restrict__ ei,
                                                unsigned char* __restrict__ A8) {
    __shared__ unsigned Acnt[8192];               // 64 rows x 512 byte-counts = 32 KB
    int bid = blockIdx.x;                         // 512 blocks
    int g = bid >> 3, sl = bid & 7;
    int v0 = sl * 64;
    int tid = threadIdx.x;
#pragma unroll
    for (int i = 0; i < 32; ++i) Acnt[tid + i * 256] = 0;
    __syncthreads();
    const int* srcp = ei + (size_t)g * 8192;
    const int* dstp = ei + E_TOTAL + (size_t)g * 8192;
    for (int i = 0; i < 32; ++i) {
        int e = tid + i * 256;
        int d = dstp[e] & 511;
        int s = srcp[e] & 511;
        if (d >= v0 && d < v0 + 64) {
            int cell = (d - v0) * 512 + s;
            atomicAdd(&Acnt[cell >> 2], 1u << ((cell & 3) << 3));
        }
    }
    __syncthreads();
#pragma unroll
    for (int j = 0; j < 32; ++j) {
        int wi = tid + j * 256;                   // u32 covers 4 cells
        unsigned wv = Acnt[wi];
        int cell0 = wi * 4;
        int row = cell0 >> 9, col0 = cell0 & 511;
        int diag = v0 + row;
        unsigned outw = 0;
#pragma unroll
        for (int h = 0; h < 4; ++h) {
            unsigned c = ((wv >> (8 * h)) & 0xFFu) + ((col0 + h == diag) ? 1u : 0u);
            outw |= c << (8 * h);
        }
        *(unsigned*)(A8 + ((size_t)(g * 512 + v0 + row) << 9) + col0) = outw;
    }
}

// W prep: transpose + bf16 hi/lo split (proven)
__global__ __launch_bounds__(256) void k_prep(const float* __restrict__ Wc,
                                              unsigned short* __restrict__ Wth,
                                              unsigned short* __restrict__ Wtl) {
    __shared__ float tile[64][65];
    int b = blockIdx.x;
    int l = b >> 2, t = b & 3;
    int k0 = (t >> 1) * 64, o0 = (t & 1) * 64;
    int lane = threadIdx.x & 63, q = threadIdx.x >> 6;
    const float* Wsrc = Wc + (size_t)l * 16384;
#pragma unroll
    for (int it = 0; it < 16; ++it) {
        int r = it * 4 + q;
        tile[r][lane] = Wsrc[(size_t)(k0 + r) * 128 + o0 + lane];
    }
    __syncthreads();
#pragma unroll
    for (int it = 0; it < 16; ++it) {
        int o = it * 4 + q;
        float v = tile[lane][o];
        unsigned short h = f2bf(v);
        unsigned short lo = f2bf(v - bf2f(h));
        size_t dst = (size_t)l * 16384 + (size_t)(o0 + o) * 128 + k0 + lane;
        Wth[dst] = h; Wtl[dst] = lo;
    }
}

// layer-0 panels: emb[x[.]] -> transposed hi/lo panels [g][128ch][512u]  (proven)
__global__ __launch_bounds__(256) void k_embT(const int* __restrict__ x,
                                              const float* __restrict__ emb,
                                              unsigned short* __restrict__ Ph,
                                              unsigned short* __restrict__ Pl) {
    __shared__ float P[64][132];
    __shared__ int nodes[64];
    int b = blockIdx.x;
    int g = b >> 3, ck = b & 7;
    int tid = threadIdx.x;
    if (tid < 64) nodes[tid] = x[g * NPG + ck * 64 + tid];
    __syncthreads();
#pragma unroll
    for (int c = 0; c < 8; ++c) {
        int idx = tid + c * 256;
        int row = idx >> 5, c4 = idx & 31;
        float4 vv = *(const float4*)(emb + (size_t)nodes[row] * 128 + c4 * 4);
        *(float4*)&P[row][c4 * 4] = vv;
    }
    __syncthreads();
#pragma unroll
    for (int c = 0; c < 4; ++c) {
        int idx = tid + c * 256;
        int ch = idx >> 3, grp = idx & 7;
        unsigned hw[4], lw[4];
#pragma unroll
        for (int j = 0; j < 4; ++j) {
            float a  = P[grp * 8 + 2 * j][ch];
            float bq = P[grp * 8 + 2 * j + 1][ch];
            unsigned short ha = f2bf(a),  hb = f2bf(bq);
            unsigned short la = f2bf(a - bf2f(ha)), lb = f2bf(bq - bf2f(hb));
            hw[j] = (unsigned)ha | ((unsigned)hb << 16);
            lw[j] = (unsigned)la | ((unsigned)lb << 16);
        }
        size_t base = ((size_t)g * 128 + ch) * 512 + ck * 64 + grp * 8;
        *(int4*)(Ph + base) = make_int4(hw[0], hw[1], hw[2], hw[3]);
        *(int4*)(Pl + base) = make_int4(lw[0], lw[1], lw[2], lw[3]);
    }
}

// ---------------- fused layer: dense MFMA; B in LDS (async dbuf), A' u8 direct-global ----
// 512 blocks (graph x 8 v-blocks of 64). No f32 Hout — output only as next panels + tmp.

__global__ __launch_bounds__(256) void k_layer(const unsigned short* __restrict__ Ph,
                                               const unsigned short* __restrict__ Pl,
                                               const unsigned char* __restrict__ A8,
                                               const unsigned short* __restrict__ Wth,
                                               const unsigned short* __restrict__ Wtl,
                                               const float* __restrict__ bvec,
                                               const float* __restrict__ Wl,
                                               const float* __restrict__ bl,
                                               float* __restrict__ tmp,
                                               unsigned short* __restrict__ Poh,
                                               unsigned short* __restrict__ Pol,
                                               const int* __restrict__ cnt,
                                               const int* __restrict__ deg) {
    __shared__ char lds[65536];
    int tid = threadIdx.x;
    int w = tid >> 6, lane = tid & 63;
    int bid = blockIdx.x;
    int g = (bid & 7) * 8 + ((bid >> 3) & 7);
    int vblk = bid >> 6;
    int nodebase = g * NPG + vblk * 64;
    int rowbase = nodebase + w * 16;
    int r = lane & 15, kb = lane >> 4;

    const unsigned short* Pgh = Ph + (size_t)g * 65536;
    const unsigned short* Pgl = Pl + (size_t)g * 65536;
    const unsigned char*  Arow8 = A8 + (size_t)(rowbase + r) * 512;

#define STAGE(buf, kt)                                                                     \
    {                                                                                      \
        _Pragma("unroll")                                                                  \
        for (int c = 0; c < 8; ++c) {                                                      \
            int sb = c * 256 + w * 64;                                                     \
            int slot = sb + lane;                                                          \
            int arr = slot >> 10;                                                          \
            int j = slot & 1023;                                                           \
            int row = j >> 3, off16 = j & 7;                                               \
            const unsigned short* src = (arr ? Pgl : Pgh)                                  \
                + (size_t)row * 512 + (kt) * 64 + ((off16 ^ (row & 7)) << 3);              \
            char* dst = lds + (buf) * 32768 + sb * 16;                                     \
            __builtin_amdgcn_global_load_lds((const unsigned*)src, (unsigned*)dst,         \
                                             16, 0, 0);                                    \
        }                                                                                  \
    }

    f32x4 acc[8];
#pragma unroll
    for (int n = 0; n < 8; ++n) acc[n] = (f32x4){0.f, 0.f, 0.f, 0.f};

    STAGE(0, 0);
    __syncthreads();
    int cbuf = 0;
    for (int kt = 0; kt < 8; ++kt) {
        if (kt < 7) STAGE(cbuf ^ 1, kt + 1);
        const char* cur = lds + cbuf * 32768;
#pragma unroll
        for (int s2 = 0; s2 < 2; ++s2) {
            uint2 w8 = *(const uint2*)(Arow8 + kt * 64 + s2 * 32 + kb * 8);
            bf16x8 aA = u8tobf(w8);
#pragma unroll
            for (int n = 0; n < 8; ++n) {
                int ch = n * 16 + r;
                int u = s2 * 4 + kb;
                int boff = ch * 128 + ((u ^ (ch & 7)) << 4);
                bf16x8 bh  = *(const bf16x8*)(cur + boff);
                bf16x8 bl2 = *(const bf16x8*)(cur + 16384 + boff);
                acc[n] = __builtin_amdgcn_mfma_f32_16x16x32_bf16(aA, bh,  acc[n], 0, 0, 0);
                acc[n] = __builtin_amdgcn_mfma_f32_16x16x32_bf16(aA, bl2, acc[n], 0, 0, 0);
            }
        }
        __syncthreads();
        cbuf ^= 1;
    }
#undef STAGE

    // ---- S -> Sb hi/lo in LDS ----
#pragma unroll
    for (int n = 0; n < 8; ++n) {
#pragma unroll
        for (int q = 0; q < 4; ++q) {
            int v64 = w * 16 + kb * 4 + q;
            int ch = n * 16 + r;
            float s = acc[n][q];
            unsigned short h = f2bf(s), lo = f2bf(s - bf2f(h));
            int addr = v64 * 256 + swz(ch * 2, v64);
            *(unsigned short*)(lds + addr)         = h;
            *(unsigned short*)(lds + 16384 + addr) = lo;
        }
    }
    __syncthreads();

    // ---- phase 2: H = tanh((S@W + (cnt+1)b)/deg) -> panels (+ tmp at l=3) ----
    bf16x8 ah[4], al[4];
#pragma unroll
    for (int ks = 0; ks < 4; ++ks) {
        int v64 = w * 16 + r;
        int addr = v64 * 256 + swz(ks * 64 + kb * 16, v64);
        ah[ks] = *(const bf16x8*)(lds + addr);
        al[ks] = *(const bf16x8*)(lds + 16384 + addr);
    }
    float invd[4], cp1[4];
#pragma unroll
    for (int q = 0; q < 4; ++q) {
        int nd = rowbase + kb * 4 + q;
        invd[q] = 1.0f / (float)deg[nd];
        cp1[q]  = (float)(cnt[nd] + 1);
    }
    float z[4] = {0.f, 0.f, 0.f, 0.f};
    unsigned hiW[8][2], loW[8][2];
#pragma unroll
    for (int ct = 0; ct < 8; ++ct) {
        const unsigned short* Wh = Wth + (size_t)(ct * 16 + r) * 128;
        const unsigned short* Wo = Wtl + (size_t)(ct * 16 + r) * 128;
        f32x4 a = {0.f, 0.f, 0.f, 0.f};
#pragma unroll
        for (int ks = 0; ks < 4; ++ks) {
            bf16x8 wh = *(const bf16x8*)(Wh + ks * 32 + kb * 8);
            bf16x8 wl = *(const bf16x8*)(Wo + ks * 32 + kb * 8);
            a = __builtin_amdgcn_mfma_f32_16x16x32_bf16(ah[ks], wh, a, 0, 0, 0);
            a = __builtin_amdgcn_mfma_f32_16x16x32_bf16(ah[ks], wl, a, 0, 0, 0);
            a = __builtin_amdgcn_mfma_f32_16x16x32_bf16(al[ks], wh, a, 0, 0, 0);
        }
        float bcol = bvec[ct * 16 + r];
        float wlast = Wl ? Wl[ct * 16 + r] : 0.f;
        unsigned short hq[4], lq[4];
#pragma unroll
        for (int q = 0; q < 4; ++q) {
            float val = tanhf((a[q] + bcol * cp1[q]) * invd[q]);
            z[q] = fmaf(val, wlast, z[q]);
            hq[q] = f2bf(val);
            lq[q] = f2bf(val - bf2f(hq[q]));
        }
        hiW[ct][0] = (unsigned)hq[0] | ((unsigned)hq[1] << 16);
        hiW[ct][1] = (unsigned)hq[2] | ((unsigned)hq[3] << 16);
        loW[ct][0] = (unsigned)lq[0] | ((unsigned)lq[1] << 16);
        loW[ct][1] = (unsigned)lq[2] | ((unsigned)lq[3] << 16);
    }

    // ---- output panels via LDS-bounce transpose (always) ----
    __syncthreads();
#pragma unroll
    for (int ct = 0; ct < 8; ++ct) {
        int o = ct * 16 + r;
        int v64 = w * 16 + kb * 4;
        int addr = o * 128 + swz(v64 * 2, o);
        *(int2*)(lds + addr)         = make_int2(hiW[ct][0], hiW[ct][1]);
        *(int2*)(lds + 16384 + addr) = make_int2(loW[ct][0], loW[ct][1]);
    }
    __syncthreads();
#pragma unroll
    for (int c = 0; c < 8; ++c) {
        int idx = tid + c * 256;
        int arr = idx >> 10;
        int j = idx & 1023;
        int o = j >> 3, off16 = j & 7;
        int4 v = *(const int4*)(lds + arr * 16384 + o * 128 + swz(off16 * 16, o));
        unsigned short* dst = (arr ? Pol : Poh) + ((size_t)g * 128 + o) * 512 + vblk * 64 + off16 * 8;
        *(int4*)dst = v;
    }

    // ---- fused last_lin (layer 3) ----
    if (Wl) {
#pragma unroll
        for (int m = 1; m < 16; m <<= 1) {
            z[0] += __shfl_xor(z[0], m); z[1] += __shfl_xor(z[1], m);
            z[2] += __shfl_xor(z[2], m); z[3] += __shfl_xor(z[3], m);
        }
        if (r == 0) {
            float b0 = bl[0];
#pragma unroll
            for (int q = 0; q < 4; ++q) tmp[rowbase + kb * 4 + q] = z[q] + b0;
        }
    }
}

// ---------------- last-channel aggregation via dense u8 A' ----------------

__global__ __launch_bounds__(256) void k_lastagg(const unsigned char* __restrict__ A8,
                                                 const float* __restrict__ tmp,
                                                 const int* __restrict__ deg,
                                                 float* __restrict__ lastc) {
    __shared__ float t[512];
    int bid = blockIdx.x;                 // 512 blocks: graph x 64-row slice
    int g = bid >> 3, sl = bid & 7;
    int tid = threadIdx.x;
    if (tid < 128) *(float4*)&t[tid * 4] = *(const float4*)(tmp + (size_t)g * 512 + tid * 4);
    __syncthreads();
    int row = tid >> 2, q = tid & 3;      // 4 threads per row, 128-col quarter each
    int v = g * NPG + sl * 64 + row;
    const unsigned char* Ar8 = A8 + ((size_t)v << 9) + q * 128;
    float s = 0.f;
#pragma unroll
    for (int c = 0; c < 128; c += 8) {
        uint2 a8 = *(const uint2*)(Ar8 + c);
#pragma unroll
        for (int h = 0; h < 4; ++h)
            s = fmaf((float)((a8.x >> (8 * h)) & 0xFFu), t[q * 128 + c + h], s);
#pragma unroll
        for (int h = 0; h < 4; ++h)
            s = fmaf((float)((a8.y >> (8 * h)) & 0xFFu), t[q * 128 + c + 4 + h], s);
    }
    s += __shfl_xor(s, 1);
    s += __shfl_xor(s, 2);
    if (q == 0) lastc[v] = tanhf(s / (float)deg[v]);
}

// ---------------- sort pool: pure bitonic (val desc, idx asc) ----------------

__global__ __launch_bounds__(256) void k_sort(const float* __restrict__ lastc,
                                              int* __restrict__ topk) {
    __shared__ float v[512];
    __shared__ int ix[512];
    int g = blockIdx.x, tid = threadIdx.x;
    for (int i = tid; i < 512; i += 256) { v[i] = lastc[g * NPG + i]; ix[i] = i; }
    __syncthreads();
    for (int ksz = 2; ksz <= 512; ksz <<= 1) {
        for (int jj = ksz >> 1; jj > 0; jj >>= 1) {
            for (int i = tid; i < 512; i += 256) {
                int p = i ^ jj;
                if (p > i) {
                    float va = v[i], vb = v[p];
                    int ia = ix[i], ib = ix[p];
                    bool b_before_a = (vb > va) || (vb == va && ib < ia);
                    bool up = (i & ksz) == 0;
                    bool sw = up ? b_before_a : !b_before_a;
                    if (sw) { v[i] = vb; v[p] = va; ix[i] = ib; ix[p] = ia; }
                }
            }
            __syncthreads();
        }
    }
    for (int k = tid; k < KTOP; k += 256) topk[g * KTOP + k] = g * NPG + ix[k];
}

// ---------------- conv1 + relu + maxpool (reads hi+lo panels, no f32 H) ----------------

__global__ __launch_bounds__(256) void k_conv1(const int* __restrict__ topk,
                                               const unsigned short* __restrict__ p1h,
                                               const unsigned short* __restrict__ p1l,
                                               const unsigned short* __restrict__ p2h,
                                               const unsigned short* __restrict__ p2l,
                                               const unsigned short* __restrict__ p3h,
                                               const unsigned short* __restrict__ p3l,
                                               const unsigned short* __restrict__ p4h,
                                               const unsigned short* __restrict__ p4l,
                                               const float* __restrict__ lastc,
                                               const float* __restrict__ c1w,
                                               const float* __restrict__ c1b,
                                               float* __restrict__ y1p) {
    __shared__ float P[16][PPAD];
    __shared__ float Y1c[16][16];
    __shared__ int nodes[16];
    int bid = blockIdx.x;
    int g = bid >> 2, cc = bid & 3;
    int tid = threadIdx.x;
    if (tid < 16) nodes[tid] = topk[g * KTOP + cc * 16 + tid];
    __syncthreads();
    {
        int r = tid >> 4, t4 = tid & 15;
        int node = nodes[r];
        int nl = node & 511;
        size_t gb = (size_t)g * 65536 + nl;
#pragma unroll
        for (int jj = 0; jj < 8; ++jj) {
            int d0 = (t4 + 16 * jj) * 4;          // 4 consecutive d, same layer
            int L = d0 >> 7;
            int ch0 = d0 & 127;
            const unsigned short* ph = (L == 0) ? p1h : (L == 1) ? p2h : (L == 2) ? p3h : p4h;
            const unsigned short* pl = (L == 0) ? p1l : (L == 1) ? p2l : (L == 2) ? p3l : p4l;
#pragma unroll
            for (int i = 0; i < 4; ++i) {
                size_t off = gb + (size_t)(ch0 + i) * 512;
                P[r][d0 + i] = bf2f(ph[off]) + bf2f(pl[off]);
            }
        }
        if (t4 == 0) P[r][512] = lastc[node];
    }
    __syncthreads();
    int o = tid >> 4, kk = tid & 15;
    const float* w = c1w + (size_t)o * LATENT;
    float a0 = 0.f, a1 = 0.f, a2 = 0.f, a3 = 0.f;
    for (int d = 0; d < 512; d += 4) {
        float4 p = *(const float4*)&P[kk][d];
        a0 = fmaf(p.x, w[d],     a0);
        a1 = fmaf(p.y, w[d + 1], a1);
        a2 = fmaf(p.z, w[d + 2], a2);
        a3 = fmaf(p.w, w[d + 3], a3);
    }
    float s = ((a0 + a1) + (a2 + a3)) + P[kk][512] * w[512] + c1b[o];
    Y1c[o][kk] = fmaxf(s, 0.f);
    __syncthreads();
    if (tid < 128) {
        int oo = tid >> 3, l = tid & 7;
        y1p[(size_t)g * 512 + oo * 32 + cc * 8 + l] = fmaxf(Y1c[oo][2 * l], Y1c[oo][2 * l + 1]);
    }
}

// ---------------- conv2 + dense + softmax ----------------

__global__ __launch_bounds__(256) void k_tail(const float* __restrict__ y1p,
                                              const float* __restrict__ c2w, const float* __restrict__ c2b,
                                              const float* __restrict__ d1w, const float* __restrict__ d1b,
                                              const float* __restrict__ d2w, const float* __restrict__ d2b,
                                              float* __restrict__ out) {
    __shared__ float Y1P[16][32];
    __shared__ float Y2[32][28];
    __shared__ float H1s[32];
    __shared__ float red[256];
    int g = blockIdx.x, tid = threadIdx.x;
    for (int t = tid; t < 512; t += 256) ((float*)Y1P)[t] = y1p[(size_t)g * 512 + t];
    __syncthreads();
    for (int t = tid; t < 32 * 28; t += 256) {
        int o2 = t / 28, tt = t - o2 * 28;
        float s = c2b[o2];
#pragma unroll
        for (int i = 0; i < 16; ++i)
#pragma unroll
            for (int dt = 0; dt < 5; ++dt)
                s = fmaf(Y1P[i][tt + dt], c2w[o2 * 80 + i * 5 + dt], s);
        Y2[o2][tt] = fmaxf(s, 0.f);
    }
    __syncthreads();
    {
        int jcol = tid >> 3, part = tid & 7;
        float s = 0.f;
        for (int rr = 0; rr < 4; ++rr) {
            int o2 = part * 4 + rr;
            int base = o2 * 28;
            for (int tt = 0; tt < 28; ++tt)
                s = fmaf(Y2[o2][tt], d1w[(size_t)(base + tt) * 32 + jcol], s);
        }
        red[tid] = s;
        __syncthreads();
        if (part == 0) {
            float t = 0.f;
#pragma unroll
            for (int p = 0; p < 8; ++p) t += red[tid + p];
            H1s[jcol] = fmaxf(t + d1b[jcol], 0.f);
        }
        __syncthreads();
    }
    if (tid == 0) {
        float l0 = d2b[0], l1 = d2b[1];
        for (int jc = 0; jc < 32; ++jc) {
            l0 = fmaf(H1s[jc], d2w[jc * 2 + 0], l0);
            l1 = fmaf(H1s[jc], d2w[jc * 2 + 1], l1);
        }
        float m = fmaxf(l0, l1);
        float e0 = expf(l0 - m), e1 = expf(l1 - m);
        float inv = 1.f / (e0 + e1);
        out[g * 2 + 0] = e0 * inv;
        out[g * 2 + 1] = e1 * inv;
    }
}

// ---------------- launch ----------------

extern "C" void kernel_launch(void* const* d_in, const int* in_sizes, int n_in,
                              void* d_out, int out_size, void* d_ws, size_t ws_size,
                              hipStream_t stream) {
    const int*   x    = (const int*)d_in[0];
    const int*   ei   = (const int*)d_in[1];
    const float* emb  = (const float*)d_in[3];
    const float* Wc   = (const float*)d_in[4];
    const float* bc   = (const float*)d_in[5];
    const float* Wl   = (const float*)d_in[6];
    const float* bl   = (const float*)d_in[7];
    const float* c1w  = (const float*)d_in[8];
    const float* c1b  = (const float*)d_in[9];
    const float* c2w  = (const float*)d_in[10];
    const float* c2b  = (const float*)d_in[11];
    const float* d1w  = (const float*)d_in[12];
    const float* d1b  = (const float*)d_in[13];
    const float* d2w  = (const float*)d_in[14];
    const float* d2b  = (const float*)d_in[15];
    float* out = (float*)d_out;

    const size_t PSZ = (size_t)NUM_GRAPHS * 128 * 512;   // panel elements

    char* ws = (char*)d_ws;
    int*   deg  = (int*)ws;            ws += (size_t)N_TOTAL * 4;
    int*   cnt  = (int*)ws;            ws += (size_t)N_TOTAL * 4;
    unsigned short* Wth = (unsigned short*)ws;  ws += (size_t)4 * 128 * 128 * 2;
    unsigned short* Wtl = (unsigned short*)ws;  ws += (size_t)4 * 128 * 128 * 2;
    float* tmp  = (float*)ws;          ws += (size_t)N_TOTAL * 4;
    float* lastc= (float*)ws;          ws += (size_t)N_TOTAL * 4;
    int*   topk = (int*)ws;            ws += (size_t)NUM_GRAPHS * KTOP * 4;
    float* y1p  = (float*)ws;          ws += (size_t)NUM_GRAPHS * 16 * 32 * 4;
    unsigned char* A8 = (unsigned char*)ws;     ws += (size_t)NUM_GRAPHS * 512 * 512;   // 16 MB
    unsigned short* PH[5];
    unsigned short* PL[5];
    for (int i = 0; i < 5; ++i) { PH[i] = (unsigned short*)ws; ws += PSZ * 2; }
    for (int i = 0; i < 5; ++i) { PL[i] = (unsigned short*)ws; ws += PSZ * 2; }

    k_init  <<<N_TOTAL / 256, 256, 0, stream>>>(deg, cnt);
    k_build <<<E_TOTAL / 256, 256, 0, stream>>>(ei, deg, cnt);
    k_prep  <<<16, 256, 0, stream>>>(Wc, Wth, Wtl);
    k_buildA<<<512, 256, 0, stream>>>(ei, A8);
    k_embT  <<<NUM_GRAPHS * 8, 256, 0, stream>>>(x, emb, PH[0], PL[0]);

    for (int l = 0; l < 4; ++l) {
        const float* wl  = (l == 3) ? Wl : nullptr;
        const float* blp = (l == 3) ? bl : nullptr;
        float*       tp  = (l == 3) ? tmp : nullptr;
        k_layer<<<512, 256, 0, stream>>>(PH[l], PL[l], A8,
                                         Wth + (size_t)l * 16384, Wtl + (size_t)l * 16384,
                                         bc + (size_t)l * 128, wl, blp, tp,
                                         PH[l + 1], PL[l + 1], cnt, deg);
    }
    k_lastagg<<<512, 256, 0, stream>>>(A8, tmp, deg, lastc);
    k_sort   <<<NUM_GRAPHS, 256, 0, stream>>>(lastc, topk);
    k_conv1  <<<NUM_GRAPHS * 4, 256, 0, stream>>>(topk, PH[1], PL[1], PH[2], PL[2],
                                                  PH[3], PL[3], PH[4], PL[4],
                                                  lastc, c1w, c1b, y1p);
    k_tail   <<<NUM_GRAPHS, 256, 0, stream>>>(y1p, c2w, c2b, d1w, d1b, d2w, d2b, out);
}